// Round 1
// baseline (1079.480 us; speedup 1.0000x reference)
//
#include <hip/hip_runtime.h>

typedef __bf16 bf16;
typedef __bf16 bf16x4 __attribute__((ext_vector_type(4)));
typedef __bf16 bf16x8 __attribute__((ext_vector_type(8)));
typedef float  f32x4  __attribute__((ext_vector_type(4)));

#define BM 128
#define BN 128
#define BK 32

__device__ __forceinline__ void async_copy16(const void* g, void* l) {
    __builtin_amdgcn_global_load_lds(
        (__attribute__((address_space(1))) void*)(g),
        (__attribute__((address_space(3))) void*)(l),
        16, 0, 0);
}

// C[m,n] = alpha * sum_k A[m,k] * B[n,k]  (both row-major; "NT" GEMM)
// Optional: per-col bias add, per-row scale, bf16 or fp32 output,
// causal block skip (S=QK^T), causal K-cap (PV).
__global__ __launch_bounds__(256)
void gemm_nt(const bf16* __restrict__ A, int lda,
             const bf16* __restrict__ B, int ldb,
             void* __restrict__ Cout, int ldc,
             int M, int N, int K,
             float alpha,
             const float* __restrict__ bias,
             const float* __restrict__ row_scale,
             int out_bf16, int causal_skip, int kcap, int row_off)
{
    int m0 = blockIdx.y * BM;
    int n0 = blockIdx.x * BN;
    if (causal_skip && n0 > row_off + m0 + BM - 1) return;  // strictly above diagonal
    int Keff = kcap ? min(K, row_off + m0 + BM) : K;

    __shared__ __attribute__((aligned(16))) bf16 As[BM * BK];  // 8 KB
    __shared__ __attribute__((aligned(16))) bf16 Bs[BN * BK];  // 8 KB

    int tid  = threadIdx.x;
    int lane = tid & 63;
    int q    = lane >> 4;    // 0..3
    int r    = lane & 15;    // 0..15
    int wave = tid >> 6;
    int wm   = (wave >> 1) * 64;
    int wn   = (wave & 1) * 64;

    f32x4 acc[4][4];
#pragma unroll
    for (int i = 0; i < 4; i++)
#pragma unroll
        for (int j = 0; j < 4; j++) acc[i][j] = (f32x4){0.f, 0.f, 0.f, 0.f};

    // staging: 256 thr x 16B = 4 KB per issue; tile = 8 KB -> 2 issues per matrix
    // LDS layout row-major 128x32 bf16 (64 B/row), row = tid>>2, col = (tid&3)*8
    const bf16* Ag = A + (size_t)(m0 + (tid >> 2)) * lda + (tid & 3) * 8;
    const bf16* Bg = B + (size_t)(n0 + (tid >> 2)) * ldb + (tid & 3) * 8;
    char* lAs = (char*)As + tid * 16;
    char* lBs = (char*)Bs + tid * 16;
    size_t astep = (size_t)64 * lda;
    size_t bstep = (size_t)64 * ldb;

    for (int k0 = 0; k0 < Keff; k0 += BK) {
        async_copy16(Ag + k0,         lAs);
        async_copy16(Ag + k0 + astep, lAs + 4096);
        async_copy16(Bg + k0,         lBs);
        async_copy16(Bg + k0 + bstep, lBs + 4096);
        asm volatile("s_waitcnt vmcnt(0)" ::: "memory");
        __syncthreads();

        bf16x8 av[4], bv[4];
#pragma unroll
        for (int mi = 0; mi < 4; mi++)
            av[mi] = *(const bf16x8*)&As[(wm + mi * 16 + r) * BK + q * 8];
#pragma unroll
        for (int ni = 0; ni < 4; ni++)
            bv[ni] = *(const bf16x8*)&Bs[(wn + ni * 16 + r) * BK + q * 8];
#pragma unroll
        for (int mi = 0; mi < 4; mi++)
#pragma unroll
            for (int ni = 0; ni < 4; ni++)
                acc[mi][ni] = __builtin_amdgcn_mfma_f32_16x16x32_bf16(
                    av[mi], bv[ni], acc[mi][ni], 0, 0, 0);
        __syncthreads();
    }

    // epilogue: C/D layout col=lane&15, row=(lane>>4)*4+j  (m89-verified)
#pragma unroll
    for (int mi = 0; mi < 4; mi++) {
#pragma unroll
        for (int ni = 0; ni < 4; ni++) {
#pragma unroll
            for (int j = 0; j < 4; j++) {
                int row = m0 + wm + mi * 16 + q * 4 + j;
                int col = n0 + wn + ni * 16 + r;
                float v = acc[mi][ni][j] * alpha;
                if (row_scale) v *= row_scale[row];
                if (bias)      v += bias[col];
                if (out_bf16)  ((bf16*)Cout)[(size_t)row * ldc + col] = (bf16)v;
                else           ((float*)Cout)[(size_t)row * ldc + col] = v;
            }
        }
    }
}

// One block per row. Reads fp32 scores row [0, t], writes unnormalized bf16
// P row [0, roundup(t+1,128)) (zeros past t), stores 1/rowsum.
__global__ __launch_bounds__(256)
void softmax_causal(const float* __restrict__ S, bf16* __restrict__ P,
                    float* __restrict__ inv_l, int T, int toff)
{
    int tr = blockIdx.x;          // local row in chunk
    int t  = toff + tr;           // global row in batch
    int L  = t + 1;
    int Lw = ((t >> 7) + 1) << 7; // round up to 128-block boundary
    const float* srow = S + (size_t)tr * T;
    bf16*        prow = P + (size_t)tr * T;
    int tid = threadIdx.x;
    __shared__ float red[8];

    float m = -3.0e38f;
    for (int s = tid; s < L; s += 256) m = fmaxf(m, srow[s]);
#pragma unroll
    for (int off = 32; off > 0; off >>= 1) m = fmaxf(m, __shfl_down(m, off, 64));
    if ((tid & 63) == 0) red[tid >> 6] = m;
    __syncthreads();
    m = fmaxf(fmaxf(red[0], red[1]), fmaxf(red[2], red[3]));
    __syncthreads();

    float sum = 0.f;
    for (int s = tid; s < Lw; s += 256) {
        float e = 0.f;
        if (s < L) { e = __expf(srow[s] - m); sum += e; }
        prow[s] = (bf16)e;
    }
#pragma unroll
    for (int off = 32; off > 0; off >>= 1) sum += __shfl_down(sum, off, 64);
    if ((tid & 63) == 0) red[tid >> 6] = sum;
    __syncthreads();
    if (tid == 0) inv_l[tr] = 1.0f / (red[0] + red[1] + red[2] + red[3]);
}

// batched transpose: V (B,T,C) -> VT (B,C,T), bf16
__global__ __launch_bounds__(256)
void transpose64(const bf16* __restrict__ V, bf16* __restrict__ VT, int T, int C)
{
    __shared__ bf16 tile[64][65];
    int b  = blockIdx.z;
    int s0 = blockIdx.x * 64, d0 = blockIdx.y * 64;
    const bf16* Vb  = V  + (size_t)b * T * C;
    bf16*       VTb = VT + (size_t)b * T * C;
    int tx = threadIdx.x & 63, ty = threadIdx.x >> 6;
#pragma unroll
    for (int i = 0; i < 64; i += 4)
        tile[ty + i][tx] = Vb[(size_t)(s0 + ty + i) * C + d0 + tx];
    __syncthreads();
#pragma unroll
    for (int i = 0; i < 64; i += 4)
        VTb[(size_t)(d0 + ty + i) * T + s0 + tx] = tile[tx][ty + i];
}

__global__ void cvt_f32_bf16(const float4* __restrict__ in, bf16x4* __restrict__ out, int n4)
{
    int i = blockIdx.x * blockDim.x + threadIdx.x;
    int stride = gridDim.x * blockDim.x;
    for (; i < n4; i += stride) {
        float4 v = in[i];
        bf16x4 o = { (bf16)v.x, (bf16)v.y, (bf16)v.z, (bf16)v.w };
        out[i] = o;
    }
}

extern "C" void kernel_launch(void* const* d_in, const int* in_sizes, int n_in,
                              void* d_out, int out_size, void* d_ws, size_t ws_size,
                              hipStream_t stream)
{
    const int B = 4, T = 4096, C = 1024, M = B * T;
    const float* x  = (const float*)d_in[0];
    const float* Wq = (const float*)d_in[1];
    const float* Wk = (const float*)d_in[2];
    const float* Wv = (const float*)d_in[3];
    const float* Wo = (const float*)d_in[4];
    const float* bo = (const float*)d_in[5];
    float* out = (float*)d_out;

    char* ws = (char*)d_ws;
    size_t off = 0;
    auto alloc = [&](size_t bytes) -> char* {
        char* p = ws + off;
        off += (bytes + 255) & ~(size_t)255;
        return p;
    };
    bf16* xb  = (bf16*)alloc((size_t)M * C * 2);   // later reused as P
    bf16* Wqb = (bf16*)alloc((size_t)C * C * 2);
    bf16* Wkb = (bf16*)alloc((size_t)C * C * 2);
    bf16* Wvb = (bf16*)alloc((size_t)C * C * 2);
    bf16* Wob = (bf16*)alloc((size_t)C * C * 2);
    bf16* Qb  = (bf16*)alloc((size_t)M * C * 2);
    bf16* Kb  = (bf16*)alloc((size_t)M * C * 2);
    bf16* VT  = (bf16*)alloc((size_t)M * C * 2);
    bf16* Ob  = (bf16*)alloc((size_t)M * C * 2);   // first V-tmp, then attn out

    // choose largest row-chunk whose fp32 score buffer fits the workspace
    int chunk = T;
    while (chunk > 128) {
        size_t need = off + ((size_t)chunk * T * 4 + 256) + ((size_t)chunk * 4 + 256);
        if (need <= ws_size) break;
        chunk >>= 1;
    }
    float* S     = (float*)alloc((size_t)chunk * T * 4);
    float* inv_l = (float*)alloc((size_t)chunk * 4);
    bf16*  P     = xb;   // x dead after projections; chunk*T*2 <= M*C*2

    dim3 blk(256);

    // fp32 -> bf16 conversions
    cvt_f32_bf16<<<dim3(4096), blk, 0, stream>>>((const float4*)x,  (bf16x4*)xb,  M * C / 4);
    cvt_f32_bf16<<<dim3(1024), blk, 0, stream>>>((const float4*)Wq, (bf16x4*)Wqb, C * C / 4);
    cvt_f32_bf16<<<dim3(1024), blk, 0, stream>>>((const float4*)Wk, (bf16x4*)Wkb, C * C / 4);
    cvt_f32_bf16<<<dim3(1024), blk, 0, stream>>>((const float4*)Wv, (bf16x4*)Wvb, C * C / 4);
    cvt_f32_bf16<<<dim3(1024), blk, 0, stream>>>((const float4*)Wo, (bf16x4*)Wob, C * C / 4);

    // projections: Q/K/V = X * W^T   (V into Ob scratch, then transpose)
    dim3 gproj(C / BN, M / BM);
    gemm_nt<<<gproj, blk, 0, stream>>>(xb, C, Wqb, C, Qb, C, M, C, C, 1.f,
                                       nullptr, nullptr, 1, 0, 0, 0);
    gemm_nt<<<gproj, blk, 0, stream>>>(xb, C, Wkb, C, Kb, C, M, C, C, 1.f,
                                       nullptr, nullptr, 1, 0, 0, 0);
    gemm_nt<<<gproj, blk, 0, stream>>>(xb, C, Wvb, C, Ob, C, M, C, C, 1.f,
                                       nullptr, nullptr, 1, 0, 0, 0);
    transpose64<<<dim3(T / 64, C / 64, B), blk, 0, stream>>>(Ob, VT, T, C);

    const float scale = 0.03125f;  // 1/sqrt(1024)
    for (int b = 0; b < B; b++) {
        for (int toff = 0; toff < T; toff += chunk) {
            // S = Q_chunk * K^T * scale   (causal block skip)
            gemm_nt<<<dim3(T / BN, chunk / BM), blk, 0, stream>>>(
                Qb + ((size_t)b * T + toff) * C, C,
                Kb + (size_t)b * T * C, C,
                S, T, chunk, T, C, scale,
                nullptr, nullptr, 0, 1, 0, toff);
            // causal softmax -> unnormalized bf16 P + 1/rowsum
            softmax_causal<<<dim3(chunk), blk, 0, stream>>>(S, P, inv_l, T, toff);
            // O = P * V  (= P * (V^T)^T, NT with K capped at diagonal block)
            gemm_nt<<<dim3(C / BN, chunk / BM), blk, 0, stream>>>(
                P, T,
                VT + (size_t)b * T * C, T,
                Ob + ((size_t)b * T + toff) * C, C, chunk, C, T, 1.f,
                nullptr, inv_l, 1, 0, 1, toff);
        }
    }

    // Y = O * Wo^T + bo  (fp32 out)
    gemm_nt<<<gproj, blk, 0, stream>>>(Ob, C, Wob, C, out, C, M, C, C, 1.f,
                                       bo, nullptr, 0, 0, 0, 0);
}

// Round 2
// 973.158 us; speedup vs baseline: 1.1093x; 1.1093x over previous
//
#include <hip/hip_runtime.h>

typedef __bf16 bf16;
typedef __bf16 bf16x4 __attribute__((ext_vector_type(4)));
typedef __bf16 bf16x8 __attribute__((ext_vector_type(8)));
typedef float  f32x4  __attribute__((ext_vector_type(4)));

#define BM 128
#define BN 128
#define BK 32

__device__ __forceinline__ void async_copy16(const void* g, void* l) {
    __builtin_amdgcn_global_load_lds(
        (__attribute__((address_space(1))) void*)(g),
        (__attribute__((address_space(3))) void*)(l),
        16, 0, 0);
}

// C[z,m,n] = alpha * rs[z,m] * sum_k A[z,m,k]*B[z,n,k]  (+bias[n])
// NT GEMM, z-batched. XOR-swizzled LDS (row-dependent k-group permute) to
// kill the 8-way bank conflicts of the 64B-row layout while keeping the
// contiguous lane->LDS mapping global_load_lds requires.
__global__ __launch_bounds__(256)
void gemm_nt(const bf16* __restrict__ A, int lda, size_t az,
             const bf16* __restrict__ B, int ldb, size_t bz,
             void* __restrict__ Cout, int ldc, size_t cz,
             int M, int N, int K, float alpha,
             const float* __restrict__ bias,
             const float* __restrict__ row_scale, int rsz,
             int out_bf16, int causal_skip, int kcap, int row_off)
{
    int z  = blockIdx.z;
    int m0 = blockIdx.y * BM;
    int n0 = blockIdx.x * BN;
    if (causal_skip && n0 > row_off + m0 + BM - 1) return;  // above diagonal
    int Keff = kcap ? min(K, row_off + m0 + BM) : K;
    A += (size_t)z * az;
    B += (size_t)z * bz;

    __shared__ __attribute__((aligned(16))) bf16 As[BM * BK];  // 8 KB
    __shared__ __attribute__((aligned(16))) bf16 Bs[BN * BK];  // 8 KB

    int tid  = threadIdx.x;
    int lane = tid & 63;
    int q    = lane >> 4;    // 0..3  (k-group)
    int r    = lane & 15;    // 0..15 (row-in-16)
    int wave = tid >> 6;
    int wm   = (wave >> 1) * 64;
    int wn   = (wave & 1) * 64;
    int sw   = (r >> 1) & 3;                // read-side swizzle
    int gsw  = ((tid & 3) ^ ((tid >> 3) & 3)) * 8;  // stage-side swizzle

    f32x4 acc[4][4];
#pragma unroll
    for (int i = 0; i < 4; i++)
#pragma unroll
        for (int j = 0; j < 4; j++) acc[i][j] = (f32x4){0.f, 0.f, 0.f, 0.f};

    // staging: thread tid fills LDS bytes [tid*16, tid*16+16); it fetches the
    // swizzled global k-group so LDS slot p of row rr holds k-group p^((rr>>1)&3)
    const bf16* Ag = A + (size_t)(m0 + (tid >> 2)) * lda + gsw;
    const bf16* Bg = B + (size_t)(n0 + (tid >> 2)) * ldb + gsw;
    char* lAs = (char*)As + tid * 16;
    char* lBs = (char*)Bs + tid * 16;
    size_t astep = (size_t)64 * lda;
    size_t bstep = (size_t)64 * ldb;

    for (int k0 = 0; k0 < Keff; k0 += BK) {
        async_copy16(Ag + k0,         lAs);
        async_copy16(Ag + k0 + astep, lAs + 4096);
        async_copy16(Bg + k0,         lBs);
        async_copy16(Bg + k0 + bstep, lBs + 4096);
        asm volatile("s_waitcnt vmcnt(0)" ::: "memory");
        __syncthreads();

        bf16x8 av[4], bv[4];
#pragma unroll
        for (int mi = 0; mi < 4; mi++)
            av[mi] = *(const bf16x8*)&As[(wm + mi * 16 + r) * BK + (q ^ sw) * 8];
#pragma unroll
        for (int ni = 0; ni < 4; ni++)
            bv[ni] = *(const bf16x8*)&Bs[(wn + ni * 16 + r) * BK + (q ^ sw) * 8];
#pragma unroll
        for (int mi = 0; mi < 4; mi++)
#pragma unroll
            for (int ni = 0; ni < 4; ni++)
                acc[mi][ni] = __builtin_amdgcn_mfma_f32_16x16x32_bf16(
                    av[mi], bv[ni], acc[mi][ni], 0, 0, 0);
        __syncthreads();
    }

    const float* rs = row_scale ? row_scale + (size_t)z * rsz : nullptr;
    // epilogue: C/D layout col=lane&15, row=(lane>>4)*4+j  (m89-verified)
#pragma unroll
    for (int mi = 0; mi < 4; mi++) {
#pragma unroll
        for (int ni = 0; ni < 4; ni++) {
#pragma unroll
            for (int j = 0; j < 4; j++) {
                int row = m0 + wm + mi * 16 + q * 4 + j;
                int col = n0 + wn + ni * 16 + r;
                float v = acc[mi][ni][j] * alpha;
                if (rs)   v *= rs[row];
                if (bias) v += bias[col];
                if (out_bf16) ((bf16*)Cout + (size_t)z * cz)[(size_t)row * ldc + col] = (bf16)v;
                else          ((float*)Cout + (size_t)z * cz)[(size_t)row * ldc + col] = v;
            }
        }
    }
}

// One block per score row. Stages the fp32 row in LDS, computes causal
// softmax, writes UNNORMALIZED bf16 P in place over the row's own bytes
// (P row base == S row base, so P's row stride is 2T bf16 elements).
// Zero-pads [L, Lw) so the PV GEMM's diagonal K-block is clean.
__global__ __launch_bounds__(256)
void softmax_causal(float* __restrict__ S, float* __restrict__ inv_l,
                    int T, int toff, int chunk)
{
    int tr = blockIdx.x, z = blockIdx.y;
    int t  = toff + tr;
    int L  = t + 1;
    int Lw = ((t >> 7) + 1) << 7;
    float* srow = S + ((size_t)z * chunk + tr) * T;
    bf16*  prow = (bf16*)srow;
    int tid = threadIdx.x;
    __shared__ float buf[4096];
    __shared__ float red[4];

    for (int s = tid * 4; s < Lw; s += 1024) {
        float4 v = *(const float4*)(srow + s);
        buf[s + 0] = (s + 0 < L) ? v.x : -3.0e38f;
        buf[s + 1] = (s + 1 < L) ? v.y : -3.0e38f;
        buf[s + 2] = (s + 2 < L) ? v.z : -3.0e38f;
        buf[s + 3] = (s + 3 < L) ? v.w : -3.0e38f;
    }
    __syncthreads();

    float m = -3.0e38f;
    for (int s = tid; s < Lw; s += 256) m = fmaxf(m, buf[s]);
#pragma unroll
    for (int off = 32; off > 0; off >>= 1) m = fmaxf(m, __shfl_down(m, off, 64));
    if ((tid & 63) == 0) red[tid >> 6] = m;
    __syncthreads();
    m = fmaxf(fmaxf(red[0], red[1]), fmaxf(red[2], red[3]));
    __syncthreads();

    float sum = 0.f;
    for (int s = tid; s < Lw; s += 256) {
        float e = __expf(buf[s] - m);   // padded lanes: exp(-huge) = 0
        sum += e;
        prow[s] = (bf16)e;
    }
#pragma unroll
    for (int off = 32; off > 0; off >>= 1) sum += __shfl_down(sum, off, 64);
    if ((tid & 63) == 0) red[tid >> 6] = sum;
    __syncthreads();
    if (tid == 0) inv_l[(size_t)z * chunk + tr] = 1.0f / (red[0] + red[1] + red[2] + red[3]);
}

// batched transpose: V (B,T,C) -> VT (B,C,T), bf16
__global__ __launch_bounds__(256)
void transpose64(const bf16* __restrict__ V, bf16* __restrict__ VT, int T, int C)
{
    __shared__ bf16 tile[64][65];
    int b  = blockIdx.z;
    int s0 = blockIdx.x * 64, d0 = blockIdx.y * 64;
    const bf16* Vb  = V  + (size_t)b * T * C;
    bf16*       VTb = VT + (size_t)b * T * C;
    int tx = threadIdx.x & 63, ty = threadIdx.x >> 6;
#pragma unroll
    for (int i = 0; i < 64; i += 4)
        tile[ty + i][tx] = Vb[(size_t)(s0 + ty + i) * C + d0 + tx];
    __syncthreads();
#pragma unroll
    for (int i = 0; i < 64; i += 4)
        VTb[(size_t)(d0 + ty + i) * T + s0 + tx] = tile[tx][ty + i];
}

__global__ void cvt_f32_bf16(const float4* __restrict__ in, bf16x4* __restrict__ out, int n4)
{
    int i = blockIdx.x * blockDim.x + threadIdx.x;
    int stride = gridDim.x * blockDim.x;
    for (; i < n4; i += stride) {
        float4 v = in[i];
        bf16x4 o = { (bf16)v.x, (bf16)v.y, (bf16)v.z, (bf16)v.w };
        out[i] = o;
    }
}

extern "C" void kernel_launch(void* const* d_in, const int* in_sizes, int n_in,
                              void* d_out, int out_size, void* d_ws, size_t ws_size,
                              hipStream_t stream)
{
    const int B = 4, T = 4096, C = 1024, M = B * T;
    const float* x  = (const float*)d_in[0];
    const float* Wq = (const float*)d_in[1];
    const float* Wk = (const float*)d_in[2];
    const float* Wv = (const float*)d_in[3];
    const float* Wo = (const float*)d_in[4];
    const float* bo = (const float*)d_in[5];
    float* out = (float*)d_out;

    char* ws = (char*)d_ws;
    size_t off = 0;
    auto alloc = [&](size_t bytes) -> char* {
        char* p = ws + off;
        off += (bytes + 255) & ~(size_t)255;
        return p;
    };
    bf16* xb  = (bf16*)alloc((size_t)M * C * 2);
    bf16* Wqb = (bf16*)alloc((size_t)C * C * 2);
    bf16* Wkb = (bf16*)alloc((size_t)C * C * 2);
    bf16* Wvb = (bf16*)alloc((size_t)C * C * 2);
    bf16* Wob = (bf16*)alloc((size_t)C * C * 2);
    bf16* Qb  = (bf16*)alloc((size_t)M * C * 2);
    bf16* Kb  = (bf16*)alloc((size_t)M * C * 2);
    bf16* VT  = (bf16*)alloc((size_t)M * C * 2);
    bf16* Ob  = (bf16*)alloc((size_t)M * C * 2);   // first V-tmp, then attn out

    // largest row-chunk (z-batched over B) whose fp32 score buffer fits;
    // chunk=1024 needs 243.3 MB total which round-0 proved available.
    int chunk = T;
    while (chunk > 128) {
        size_t need = off + (((size_t)B * chunk * T * 4 + 255) & ~(size_t)255)
                          + (((size_t)B * chunk * 4 + 255) & ~(size_t)255);
        if (need <= ws_size) break;
        chunk >>= 1;
    }
    float* S     = (float*)alloc((size_t)B * chunk * T * 4);
    float* inv_l = (float*)alloc((size_t)B * chunk * 4);

    dim3 blk(256);

    // fp32 -> bf16 conversions
    cvt_f32_bf16<<<dim3(4096), blk, 0, stream>>>((const float4*)x,  (bf16x4*)xb,  M * C / 4);
    cvt_f32_bf16<<<dim3(1024), blk, 0, stream>>>((const float4*)Wq, (bf16x4*)Wqb, C * C / 4);
    cvt_f32_bf16<<<dim3(1024), blk, 0, stream>>>((const float4*)Wk, (bf16x4*)Wkb, C * C / 4);
    cvt_f32_bf16<<<dim3(1024), blk, 0, stream>>>((const float4*)Wv, (bf16x4*)Wvb, C * C / 4);
    cvt_f32_bf16<<<dim3(1024), blk, 0, stream>>>((const float4*)Wo, (bf16x4*)Wob, C * C / 4);

    // projections: Q/K/V = X * W^T   (V into Ob scratch, then transpose)
    dim3 gproj(C / BN, M / BM, 1);
    gemm_nt<<<gproj, blk, 0, stream>>>(xb, C, 0, Wqb, C, 0, Qb, C, 0, M, C, C, 1.f,
                                       nullptr, nullptr, 0, 1, 0, 0, 0);
    gemm_nt<<<gproj, blk, 0, stream>>>(xb, C, 0, Wkb, C, 0, Kb, C, 0, M, C, C, 1.f,
                                       nullptr, nullptr, 0, 1, 0, 0, 0);
    gemm_nt<<<gproj, blk, 0, stream>>>(xb, C, 0, Wvb, C, 0, Ob, C, 0, M, C, C, 1.f,
                                       nullptr, nullptr, 0, 1, 0, 0, 0);
    transpose64<<<dim3(T / 64, C / 64, B), blk, 0, stream>>>(Ob, VT, T, C);

    const float scale = 0.03125f;  // 1/sqrt(1024)
    for (int toff = 0; toff < T; toff += chunk) {
        // S = Q_chunk * K^T * scale   (z = batch, causal block skip)
        gemm_nt<<<dim3(T / BN, chunk / BM, B), blk, 0, stream>>>(
            Qb + (size_t)toff * C, C, (size_t)T * C,
            Kb, C, (size_t)T * C,
            S, T, (size_t)chunk * T,
            chunk, T, C, scale,
            nullptr, nullptr, 0, 0, 1, 0, toff);
        // causal softmax -> unnormalized bf16 P in place + 1/rowsum
        softmax_causal<<<dim3(chunk, B), blk, 0, stream>>>(S, inv_l, T, toff, chunk);
        // O = P * V^T^T  (NT, K capped at diagonal block, row-scaled by 1/l)
        gemm_nt<<<dim3(C / BN, chunk / BM, B), blk, 0, stream>>>(
            (const bf16*)S, 2 * T, (size_t)chunk * 2 * T,
            VT, T, (size_t)T * C,
            Ob + (size_t)toff * C, C, (size_t)T * C,
            chunk, C, T, 1.f,
            nullptr, inv_l, chunk, 1, 0, 1, toff);
    }

    // Y = O * Wo^T + bo  (fp32 out)
    gemm_nt<<<gproj, blk, 0, stream>>>(Ob, C, 0, Wob, C, 0, out, C, 0, M, C, C, 1.f,
                                       bo, nullptr, 0, 0, 0, 0, 0);
}

// Round 3
// 768.708 us; speedup vs baseline: 1.4043x; 1.2660x over previous
//
#include <hip/hip_runtime.h>

typedef __bf16 bf16;
typedef __bf16 bf16x4 __attribute__((ext_vector_type(4)));
typedef __bf16 bf16x8 __attribute__((ext_vector_type(8)));
typedef float  f32x4  __attribute__((ext_vector_type(4)));

#define BM 128
#define BN 128
#define BK 32

__device__ __forceinline__ void async_copy16(const void* g, void* l) {
    __builtin_amdgcn_global_load_lds(
        (__attribute__((address_space(1))) void*)(g),
        (__attribute__((address_space(3))) void*)(l),
        16, 0, 0);
}

// C[z,m,n] = alpha * rs[z,m] * sum_k A[z,m,k]*B[z,n,k]  (+bias[n])
// NT GEMM, z-batched, XOR-swizzled LDS (conflict-free, verified round 2).
// qkv_mode: N spans 3 concatenated 1024-col output buffers C0/C1/C2.
__global__ __launch_bounds__(256)
void gemm_nt(const bf16* __restrict__ A, int lda, size_t az,
             const bf16* __restrict__ B, int ldb, size_t bz,
             void* __restrict__ C0, void* __restrict__ C1, void* __restrict__ C2,
             int ldc, size_t cz,
             int M, int N, int K, float alpha,
             const float* __restrict__ bias,
             const float* __restrict__ row_scale, int rsz,
             int out_bf16, int qkv_mode, int causal_skip, int kcap, int row_off)
{
    int z  = blockIdx.z;
    int m0 = blockIdx.y * BM;
    int n0 = blockIdx.x * BN;
    if (causal_skip && n0 > row_off + m0 + BM - 1) return;  // above diagonal
    int Keff = kcap ? min(K, row_off + m0 + BM) : K;
    A += (size_t)z * az;
    B += (size_t)z * bz;

    __shared__ __attribute__((aligned(16))) bf16 As[BM * BK];  // 8 KB
    __shared__ __attribute__((aligned(16))) bf16 Bs[BN * BK];  // 8 KB

    int tid  = threadIdx.x;
    int lane = tid & 63;
    int q    = lane >> 4;    // 0..3  (k-group)
    int r    = lane & 15;    // 0..15 (row-in-16)
    int wave = tid >> 6;
    int wm   = (wave >> 1) * 64;
    int wn   = (wave & 1) * 64;
    int sw   = (r >> 1) & 3;                        // read-side swizzle
    int gsw  = ((tid & 3) ^ ((tid >> 3) & 3)) * 8;  // stage-side swizzle

    f32x4 acc[4][4];
#pragma unroll
    for (int i = 0; i < 4; i++)
#pragma unroll
        for (int j = 0; j < 4; j++) acc[i][j] = (f32x4){0.f, 0.f, 0.f, 0.f};

    const bf16* Ag = A + (size_t)(m0 + (tid >> 2)) * lda + gsw;
    const bf16* Bg = B + (size_t)(n0 + (tid >> 2)) * ldb + gsw;
    char* lAs = (char*)As + tid * 16;
    char* lBs = (char*)Bs + tid * 16;
    size_t astep = (size_t)64 * lda;
    size_t bstep = (size_t)64 * ldb;

    for (int k0 = 0; k0 < Keff; k0 += BK) {
        async_copy16(Ag + k0,         lAs);
        async_copy16(Ag + k0 + astep, lAs + 4096);
        async_copy16(Bg + k0,         lBs);
        async_copy16(Bg + k0 + bstep, lBs + 4096);
        asm volatile("s_waitcnt vmcnt(0)" ::: "memory");
        __syncthreads();

        bf16x8 av[4], bv[4];
#pragma unroll
        for (int mi = 0; mi < 4; mi++)
            av[mi] = *(const bf16x8*)&As[(wm + mi * 16 + r) * BK + (q ^ sw) * 8];
#pragma unroll
        for (int ni = 0; ni < 4; ni++)
            bv[ni] = *(const bf16x8*)&Bs[(wn + ni * 16 + r) * BK + (q ^ sw) * 8];
#pragma unroll
        for (int mi = 0; mi < 4; mi++)
#pragma unroll
            for (int ni = 0; ni < 4; ni++)
                acc[mi][ni] = __builtin_amdgcn_mfma_f32_16x16x32_bf16(
                    av[mi], bv[ni], acc[mi][ni], 0, 0, 0);
        __syncthreads();
    }

    const float* rs = row_scale ? row_scale + (size_t)z * rsz : nullptr;
    void* Cb = C0;
    if (qkv_mode) { int sel = n0 >> 10; Cb = sel == 0 ? C0 : (sel == 1 ? C1 : C2); }
    // epilogue: C/D layout col=lane&15, row=(lane>>4)*4+j  (m89-verified)
#pragma unroll
    for (int mi = 0; mi < 4; mi++) {
#pragma unroll
        for (int ni = 0; ni < 4; ni++) {
#pragma unroll
            for (int j = 0; j < 4; j++) {
                int row = m0 + wm + mi * 16 + q * 4 + j;
                int col = n0 + wn + ni * 16 + r;
                if (qkv_mode) col &= 1023;
                float v = acc[mi][ni][j] * alpha;
                if (rs)   v *= rs[row];
                if (bias) v += bias[col];
                if (out_bf16) ((bf16*)Cb + (size_t)z * cz)[(size_t)row * ldc + col] = (bf16)v;
                else          ((float*)Cb + (size_t)z * cz)[(size_t)row * ldc + col] = v;
            }
        }
    }
}

// One block per score row, bf16 scores in/out IN PLACE (row stride T bf16).
// Writes unnormalized P (zero-padded to the 128-block boundary) + 1/rowsum.
__global__ __launch_bounds__(256)
void softmax_causal(bf16* __restrict__ S, float* __restrict__ inv_l,
                    int T, int toff, int chunk)
{
    int tr = blockIdx.x, z = blockIdx.y;
    int t  = toff + tr;
    int L  = t + 1;
    int Lw = ((t >> 7) + 1) << 7;
    bf16* row = S + ((size_t)z * chunk + tr) * T;
    int tid = threadIdx.x;
    __shared__ float buf[4096];
    __shared__ float red[4];

    for (int s = tid * 8; s < Lw; s += 2048) {
        bf16x8 v = *(const bf16x8*)(row + s);
#pragma unroll
        for (int i = 0; i < 8; i++)
            buf[s + i] = (s + i < L) ? (float)v[i] : -3.0e38f;
    }
    __syncthreads();

    float m = -3.0e38f;
    for (int s = tid; s < Lw; s += 256) m = fmaxf(m, buf[s]);
#pragma unroll
    for (int off = 32; off > 0; off >>= 1) m = fmaxf(m, __shfl_down(m, off, 64));
    if ((tid & 63) == 0) red[tid >> 6] = m;
    __syncthreads();
    m = fmaxf(fmaxf(red[0], red[1]), fmaxf(red[2], red[3]));
    __syncthreads();

    float sum = 0.f;
    for (int s = tid * 8; s < Lw; s += 2048) {
        bf16x8 o;
#pragma unroll
        for (int i = 0; i < 8; i++) {
            float e = __expf(buf[s + i] - m);  // padded lanes -> 0
            sum += e;
            o[i] = (bf16)e;
        }
        *(bf16x8*)(row + s) = o;
    }
#pragma unroll
    for (int off = 32; off > 0; off >>= 1) sum += __shfl_down(sum, off, 64);
    if ((tid & 63) == 0) red[tid >> 6] = sum;
    __syncthreads();
    if (tid == 0) inv_l[(size_t)z * chunk + tr] = 1.0f / (red[0] + red[1] + red[2] + red[3]);
}

// batched transpose: V (B,T,C) -> VT (B,C,T), bf16
__global__ __launch_bounds__(256)
void transpose64(const bf16* __restrict__ V, bf16* __restrict__ VT, int T, int C)
{
    __shared__ bf16 tile[64][65];
    int b  = blockIdx.z;
    int s0 = blockIdx.x * 64, d0 = blockIdx.y * 64;
    const bf16* Vb  = V  + (size_t)b * T * C;
    bf16*       VTb = VT + (size_t)b * T * C;
    int tx = threadIdx.x & 63, ty = threadIdx.x >> 6;
#pragma unroll
    for (int i = 0; i < 64; i += 4)
        tile[ty + i][tx] = Vb[(size_t)(s0 + ty + i) * C + d0 + tx];
    __syncthreads();
#pragma unroll
    for (int i = 0; i < 64; i += 4)
        VTb[(size_t)(d0 + ty + i) * T + s0 + tx] = tile[tx][ty + i];
}

__global__ void cvt_f32_bf16(const float4* __restrict__ in, bf16x4* __restrict__ out, int n4)
{
    int i = blockIdx.x * blockDim.x + threadIdx.x;
    int stride = gridDim.x * blockDim.x;
    for (; i < n4; i += stride) {
        float4 v = in[i];
        bf16x4 o = { (bf16)v.x, (bf16)v.y, (bf16)v.z, (bf16)v.w };
        out[i] = o;
    }
}

extern "C" void kernel_launch(void* const* d_in, const int* in_sizes, int n_in,
                              void* d_out, int out_size, void* d_ws, size_t ws_size,
                              hipStream_t stream)
{
    const int B = 4, T = 4096, C = 1024, M = B * T;
    const float* x  = (const float*)d_in[0];
    const float* Wq = (const float*)d_in[1];
    const float* Wk = (const float*)d_in[2];
    const float* Wv = (const float*)d_in[3];
    const float* Wo = (const float*)d_in[4];
    const float* bo = (const float*)d_in[5];
    float* out = (float*)d_out;

    char* ws = (char*)d_ws;
    size_t off = 0;
    auto alloc = [&](size_t bytes) -> char* {
        char* p = ws + off;
        off += (bytes + 255) & ~(size_t)255;
        return p;
    };
    bf16* Wcat = (bf16*)alloc((size_t)3 * C * C * 2);  // [Wq; Wk; Wv]
    bf16* Wob  = (bf16*)alloc((size_t)C * C * 2);
    bf16* Qb   = (bf16*)alloc((size_t)M * C * 2);
    bf16* Kb   = (bf16*)alloc((size_t)M * C * 2);
    bf16* VT   = (bf16*)alloc((size_t)M * C * 2);
    bf16* Ob   = (bf16*)alloc((size_t)M * C * 2);    // first V-tmp, then attn out

    // bf16 score buffer (B, chunk, T); xb overlays its start (chunk>=1024
    // guarantees >= 32 MB). chunk=1024 floor needs ~169 MB (ws proven >=243).
    int chunk = T;
    while (chunk > 1024) {
        size_t need = off + (((size_t)B * chunk * T * 2 + 255) & ~(size_t)255)
                          + (((size_t)B * chunk * 4 + 255) & ~(size_t)255);
        if (need <= ws_size) break;
        chunk >>= 1;
    }
    bf16*  S     = (bf16*)alloc((size_t)B * chunk * T * 2);
    float* inv_l = (float*)alloc((size_t)B * chunk * 4);
    bf16*  xb    = S;  // x dead after QKV projection

    dim3 blk(256);

    cvt_f32_bf16<<<dim3(4096), blk, 0, stream>>>((const float4*)x,  (bf16x4*)xb, M * C / 4);
    cvt_f32_bf16<<<dim3(1024), blk, 0, stream>>>((const float4*)Wq, (bf16x4*)(Wcat),             C * C / 4);
    cvt_f32_bf16<<<dim3(1024), blk, 0, stream>>>((const float4*)Wk, (bf16x4*)(Wcat + C * C),     C * C / 4);
    cvt_f32_bf16<<<dim3(1024), blk, 0, stream>>>((const float4*)Wv, (bf16x4*)(Wcat + 2 * C * C), C * C / 4);
    cvt_f32_bf16<<<dim3(1024), blk, 0, stream>>>((const float4*)Wo, (bf16x4*)Wob, C * C / 4);

    // fused QKV projection: [Q|K|V] = X * Wcat^T  (V into Ob scratch)
    gemm_nt<<<dim3(3 * C / BN, M / BM, 1), blk, 0, stream>>>(
        xb, C, 0, Wcat, C, 0, Qb, Kb, Ob, C, 0, M, 3 * C, C, 1.f,
        nullptr, nullptr, 0, 1, 1, 0, 0, 0);
    transpose64<<<dim3(T / 64, C / 64, B), blk, 0, stream>>>(Ob, VT, T, C);

    const float scale = 0.03125f;  // 1/sqrt(1024)
    for (int toff = 0; toff < T; toff += chunk) {
        // S = Q_chunk * K^T * scale  (bf16 out, causal block skip)
        gemm_nt<<<dim3(T / BN, chunk / BM, B), blk, 0, stream>>>(
            Qb + (size_t)toff * C, C, (size_t)T * C,
            Kb, C, (size_t)T * C,
            S, nullptr, nullptr, T, (size_t)chunk * T,
            chunk, T, C, scale,
            nullptr, nullptr, 0, 1, 0, 1, 0, toff);
        // causal softmax in place -> unnormalized bf16 P + 1/rowsum
        softmax_causal<<<dim3(chunk, B), blk, 0, stream>>>(S, inv_l, T, toff, chunk);
        // O = P * V  (NT vs VT, K capped at diagonal block, scaled by 1/l)
        gemm_nt<<<dim3(C / BN, chunk / BM, B), blk, 0, stream>>>(
            S, T, (size_t)chunk * T,
            VT, T, (size_t)T * C,
            Ob + (size_t)toff * C, nullptr, nullptr, C, (size_t)T * C,
            chunk, C, T, 1.f,
            nullptr, inv_l, chunk, 1, 0, 0, 1, toff);
    }

    // Y = O * Wo^T + bo  (fp32 out)
    gemm_nt<<<dim3(C / BN, M / BM, 1), blk, 0, stream>>>(
        Ob, C, 0, Wob, C, 0, out, nullptr, nullptr, C, 0, M, C, C, 1.f,
        bo, nullptr, 0, 0, 0, 0, 0, 0);
}

// Round 4
// 716.701 us; speedup vs baseline: 1.5062x; 1.0726x over previous
//
#include <hip/hip_runtime.h>

typedef __bf16 bf16;
typedef __bf16 bf16x4 __attribute__((ext_vector_type(4)));
typedef __bf16 bf16x8 __attribute__((ext_vector_type(8)));
typedef float  f32x4  __attribute__((ext_vector_type(4)));

#define BM 128
#define BN 128
#define BK 32

__device__ __forceinline__ void async_copy16(const void* g, void* l) {
    __builtin_amdgcn_global_load_lds(
        (__attribute__((address_space(1))) void*)(g),
        (__attribute__((address_space(3))) void*)(l),
        16, 0, 0);
}

// C[z,m,n] = alpha * rs[z,m] * sum_k A[z,m,k]*B[z,n,k]  (+bias[n])
// NT GEMM, z-batched, XOR-swizzled LDS (conflict-free, verified round 2).
// qkv_mode: N spans 3 concatenated 1024-col output buffers C0/C1/C2.
// rev_m: longest-work-first block order for triangular (causal/kcap) grids.
__global__ __launch_bounds__(256)
void gemm_nt(const bf16* __restrict__ A, int lda, size_t az,
             const bf16* __restrict__ B, int ldb, size_t bz,
             void* __restrict__ C0, void* __restrict__ C1, void* __restrict__ C2,
             int ldc, size_t cz,
             int M, int N, int K, float alpha,
             const float* __restrict__ bias,
             const float* __restrict__ row_scale, int rsz,
             int out_bf16, int qkv_mode, int causal_skip, int kcap,
             int row_off, int rev_m)
{
    int z  = blockIdx.z;
    int by = rev_m ? (gridDim.y - 1 - blockIdx.y) : blockIdx.y;
    int m0 = by * BM;
    int n0 = blockIdx.x * BN;
    if (causal_skip && n0 > row_off + m0 + BM - 1) return;  // above diagonal
    int Keff = kcap ? min(K, row_off + m0 + BM) : K;
    A += (size_t)z * az;
    B += (size_t)z * bz;

    __shared__ __attribute__((aligned(16))) bf16 As[BM * BK];  // 8 KB
    __shared__ __attribute__((aligned(16))) bf16 Bs[BN * BK];  // 8 KB

    int tid  = threadIdx.x;
    int lane = tid & 63;
    int q    = lane >> 4;    // 0..3  (k-group)
    int r    = lane & 15;    // 0..15 (row-in-16)
    int wave = tid >> 6;
    int wm   = (wave >> 1) * 64;
    int wn   = (wave & 1) * 64;
    int sw   = (r >> 1) & 3;                        // read-side swizzle
    int gsw  = ((tid & 3) ^ ((tid >> 3) & 3)) * 8;  // stage-side swizzle

    f32x4 acc[4][4];
#pragma unroll
    for (int i = 0; i < 4; i++)
#pragma unroll
        for (int j = 0; j < 4; j++) acc[i][j] = (f32x4){0.f, 0.f, 0.f, 0.f};

    const bf16* Ag = A + (size_t)(m0 + (tid >> 2)) * lda + gsw;
    const bf16* Bg = B + (size_t)(n0 + (tid >> 2)) * ldb + gsw;
    char* lAs = (char*)As + tid * 16;
    char* lBs = (char*)Bs + tid * 16;
    size_t astep = (size_t)64 * lda;
    size_t bstep = (size_t)64 * ldb;

    for (int k0 = 0; k0 < Keff; k0 += BK) {
        async_copy16(Ag + k0,         lAs);
        async_copy16(Ag + k0 + astep, lAs + 4096);
        async_copy16(Bg + k0,         lBs);
        async_copy16(Bg + k0 + bstep, lBs + 4096);
        asm volatile("s_waitcnt vmcnt(0)" ::: "memory");
        __syncthreads();

        bf16x8 av[4], bv[4];
#pragma unroll
        for (int mi = 0; mi < 4; mi++)
            av[mi] = *(const bf16x8*)&As[(wm + mi * 16 + r) * BK + (q ^ sw) * 8];
#pragma unroll
        for (int ni = 0; ni < 4; ni++)
            bv[ni] = *(const bf16x8*)&Bs[(wn + ni * 16 + r) * BK + (q ^ sw) * 8];
#pragma unroll
        for (int mi = 0; mi < 4; mi++)
#pragma unroll
            for (int ni = 0; ni < 4; ni++)
                acc[mi][ni] = __builtin_amdgcn_mfma_f32_16x16x32_bf16(
                    av[mi], bv[ni], acc[mi][ni], 0, 0, 0);
        __syncthreads();
    }

    const float* rs = row_scale ? row_scale + (size_t)z * rsz : nullptr;
    void* Cb = C0;
    if (qkv_mode) { int sel = n0 >> 10; Cb = sel == 0 ? C0 : (sel == 1 ? C1 : C2); }
    // epilogue: C/D layout col=lane&15, row=(lane>>4)*4+j  (m89-verified)
#pragma unroll
    for (int mi = 0; mi < 4; mi++) {
#pragma unroll
        for (int ni = 0; ni < 4; ni++) {
#pragma unroll
            for (int j = 0; j < 4; j++) {
                int row = m0 + wm + mi * 16 + q * 4 + j;
                int col = n0 + wn + ni * 16 + r;
                if (qkv_mode) col &= 1023;
                float v = acc[mi][ni][j] * alpha;
                if (rs)   v *= rs[row];
                if (bias) v += bias[col];
                if (out_bf16) ((bf16*)Cb + (size_t)z * cz)[(size_t)row * ldc + col] = (bf16)v;
                else          ((float*)Cb + (size_t)z * cz)[(size_t)row * ldc + col] = v;
            }
        }
    }
}

// One block per score row, bf16 scores in/out IN PLACE (row stride T bf16).
// Writes unnormalized P (zero-padded to the 128-block boundary) + 1/rowsum.
__global__ __launch_bounds__(256)
void softmax_causal(bf16* __restrict__ S, float* __restrict__ inv_l,
                    int T, int toff, int chunk)
{
    int tr = blockIdx.x, z = blockIdx.y;
    int t  = toff + tr;
    int L  = t + 1;
    int Lw = ((t >> 7) + 1) << 7;
    bf16* row = S + ((size_t)z * chunk + tr) * T;
    int tid = threadIdx.x;
    __shared__ float buf[4096];
    __shared__ float red[4];

    for (int s = tid * 8; s < Lw; s += 2048) {
        bf16x8 v = *(const bf16x8*)(row + s);
#pragma unroll
        for (int i = 0; i < 8; i++)
            buf[s + i] = (s + i < L) ? (float)v[i] : -3.0e38f;
    }
    __syncthreads();

    float m = -3.0e38f;
    for (int s = tid; s < Lw; s += 256) m = fmaxf(m, buf[s]);
#pragma unroll
    for (int off = 32; off > 0; off >>= 1) m = fmaxf(m, __shfl_down(m, off, 64));
    if ((tid & 63) == 0) red[tid >> 6] = m;
    __syncthreads();
    m = fmaxf(fmaxf(red[0], red[1]), fmaxf(red[2], red[3]));
    __syncthreads();

    float sum = 0.f;
    for (int s = tid * 8; s < Lw; s += 2048) {
        bf16x8 o;
#pragma unroll
        for (int i = 0; i < 8; i++) {
            float e = __expf(buf[s + i] - m);  // padded lanes -> 0
            sum += e;
            o[i] = (bf16)e;
        }
        *(bf16x8*)(row + s) = o;
    }
#pragma unroll
    for (int off = 32; off > 0; off >>= 1) sum += __shfl_down(sum, off, 64);
    if ((tid & 63) == 0) red[tid >> 6] = sum;
    __syncthreads();
    if (tid == 0) inv_l[(size_t)z * chunk + tr] = 1.0f / (red[0] + red[1] + red[2] + red[3]);
}

// batched transpose: V (B,T,C) -> VT (B,C,T), bf16
__global__ __launch_bounds__(256)
void transpose64(const bf16* __restrict__ V, bf16* __restrict__ VT, int T, int C)
{
    __shared__ bf16 tile[64][65];
    int b  = blockIdx.z;
    int s0 = blockIdx.x * 64, d0 = blockIdx.y * 64;
    const bf16* Vb  = V  + (size_t)b * T * C;
    bf16*       VTb = VT + (size_t)b * T * C;
    int tx = threadIdx.x & 63, ty = threadIdx.x >> 6;
#pragma unroll
    for (int i = 0; i < 64; i += 4)
        tile[ty + i][tx] = Vb[(size_t)(s0 + ty + i) * C + d0 + tx];
    __syncthreads();
#pragma unroll
    for (int i = 0; i < 64; i += 4)
        VTb[(size_t)(d0 + ty + i) * T + s0 + tx] = tile[tx][ty + i];
}

__global__ void cvt_f32_bf16(const float4* __restrict__ in, bf16x4* __restrict__ out, int n4)
{
    int i = blockIdx.x * blockDim.x + threadIdx.x;
    int stride = gridDim.x * blockDim.x;
    for (; i < n4; i += stride) {
        float4 v = in[i];
        bf16x4 o = { (bf16)v.x, (bf16)v.y, (bf16)v.z, (bf16)v.w };
        out[i] = o;
    }
}

extern "C" void kernel_launch(void* const* d_in, const int* in_sizes, int n_in,
                              void* d_out, int out_size, void* d_ws, size_t ws_size,
                              hipStream_t stream)
{
    const int B = 4, T = 4096, C = 1024, M = B * T;
    const float* x  = (const float*)d_in[0];
    const float* Wq = (const float*)d_in[1];
    const float* Wk = (const float*)d_in[2];
    const float* Wv = (const float*)d_in[3];
    const float* Wo = (const float*)d_in[4];
    const float* bo = (const float*)d_in[5];
    float* out = (float*)d_out;

    char* ws = (char*)d_ws;
    size_t off = 0;
    auto alloc = [&](size_t bytes) -> char* {
        char* p = ws + off;
        off += (bytes + 255) & ~(size_t)255;
        return p;
    };
    bf16* Wcat = (bf16*)alloc((size_t)3 * C * C * 2);  // [Wq; Wk; Wv]
    bf16* Wob  = (bf16*)alloc((size_t)C * C * 2);
    bf16* Qb   = (bf16*)alloc((size_t)M * C * 2);
    bf16* Kb   = (bf16*)alloc((size_t)M * C * 2);
    bf16* VT   = (bf16*)alloc((size_t)M * C * 2);

    // Preferred plan (chunk = T, ~232 MB — ws proven >= 235 MB in round 1):
    //   S region (B*T*T*2 = 128 MB) hosts xb [0,32MB) and raw-V [32,64MB)
    //   during the projection phase (both dead before S is written);
    //   attention output O aliases Qb (Q dead after the single S-GEMM).
    // Fallback (smaller ws): separate Ob, chunked loop (round-2 scheme).
    size_t base = off;
    int chunk = T;
    bf16 *S, *xb, *Vtmp, *Ob;
    float* inv_l;
    {
        size_t need = base + (((size_t)B * T * T * 2 + 255) & ~(size_t)255)
                           + (((size_t)B * T * 4 + 255) & ~(size_t)255);
        if (need <= ws_size) {
            S     = (bf16*)alloc((size_t)B * T * T * 2);
            inv_l = (float*)alloc((size_t)B * T * 4);
            xb    = S;
            Vtmp  = S + (size_t)M * C;   // 32 MB past xb, inside S region
            Ob    = Qb;                  // O overwrites Q after S-GEMM
        } else {
            Ob = (bf16*)alloc((size_t)M * C * 2);
            chunk = T / 2;
            while (chunk > 1024) {
                size_t nd = off + (((size_t)B * chunk * T * 2 + 255) & ~(size_t)255)
                                + (((size_t)B * chunk * 4 + 255) & ~(size_t)255);
                if (nd <= ws_size) break;
                chunk >>= 1;
            }
            S     = (bf16*)alloc((size_t)B * chunk * T * 2);
            inv_l = (float*)alloc((size_t)B * chunk * 4);
            xb    = S;   // x dead after QKV projection
            Vtmp  = Ob;  // V staged in Ob, transposed before PV writes Ob
        }
    }

    dim3 blk(256);

    cvt_f32_bf16<<<dim3(4096), blk, 0, stream>>>((const float4*)x,  (bf16x4*)xb, M * C / 4);
    cvt_f32_bf16<<<dim3(1024), blk, 0, stream>>>((const float4*)Wq, (bf16x4*)(Wcat),             C * C / 4);
    cvt_f32_bf16<<<dim3(1024), blk, 0, stream>>>((const float4*)Wk, (bf16x4*)(Wcat + C * C),     C * C / 4);
    cvt_f32_bf16<<<dim3(1024), blk, 0, stream>>>((const float4*)Wv, (bf16x4*)(Wcat + 2 * C * C), C * C / 4);
    cvt_f32_bf16<<<dim3(1024), blk, 0, stream>>>((const float4*)Wo, (bf16x4*)Wob, C * C / 4);

    // fused QKV projection: [Q|K|V] = X * Wcat^T
    gemm_nt<<<dim3(3 * C / BN, M / BM, 1), blk, 0, stream>>>(
        xb, C, 0, Wcat, C, 0, Qb, Kb, Vtmp, C, 0, M, 3 * C, C, 1.f,
        nullptr, nullptr, 0, 1, 1, 0, 0, 0, 0);
    transpose64<<<dim3(T / 64, C / 64, B), blk, 0, stream>>>(Vtmp, VT, T, C);

    const float scale = 0.03125f;  // 1/sqrt(1024)
    for (int toff = 0; toff < T; toff += chunk) {
        // S = Q_chunk * K^T * scale  (bf16 out, causal skip, longest-m first)
        gemm_nt<<<dim3(T / BN, chunk / BM, B), blk, 0, stream>>>(
            Qb + (size_t)toff * C, C, (size_t)T * C,
            Kb, C, (size_t)T * C,
            S, nullptr, nullptr, T, (size_t)chunk * T,
            chunk, T, C, scale,
            nullptr, nullptr, 0, 1, 0, 1, 0, toff, 1);
        // causal softmax in place -> unnormalized bf16 P + 1/rowsum
        softmax_causal<<<dim3(chunk, B), blk, 0, stream>>>(S, inv_l, T, toff, chunk);
        // O = P * V  (NT vs VT, K capped at diagonal, scaled by 1/l, longest first)
        gemm_nt<<<dim3(C / BN, chunk / BM, B), blk, 0, stream>>>(
            S, T, (size_t)chunk * T,
            VT, T, (size_t)T * C,
            Ob + (size_t)toff * C, nullptr, nullptr, C, (size_t)T * C,
            chunk, C, T, 1.f,
            nullptr, inv_l, chunk, 1, 0, 0, 1, toff, 1);
    }

    // Y = O * Wo^T + bo  (fp32 out)
    gemm_nt<<<dim3(C / BN, M / BM, 1), blk, 0, stream>>>(
        Ob, C, 0, Wob, C, 0, out, nullptr, nullptr, C, 0, M, C, C, 1.f,
        bo, nullptr, 0, 0, 0, 0, 0, 0, 0);
}

// Round 5
// 639.875 us; speedup vs baseline: 1.6870x; 1.1201x over previous
//
#include <hip/hip_runtime.h>

typedef __bf16 bf16;
typedef __bf16 bf16x4 __attribute__((ext_vector_type(4)));
typedef __bf16 bf16x8 __attribute__((ext_vector_type(8)));
typedef float  f32x4  __attribute__((ext_vector_type(4)));

#define BM 128
#define BN 128
#define BK 64

__device__ __forceinline__ void async_copy16(const void* g, void* l) {
    __builtin_amdgcn_global_load_lds(
        (__attribute__((address_space(1))) void*)(g),
        (__attribute__((address_space(3))) void*)(l),
        16, 0, 0);
}

// C[z,m,n] = alpha * rs[z,m] * sum_k A[z,m,k]*B[z,n,k]  (+bias[n])
// NT GEMM, z-batched, BK=64 (half the vmcnt-drain/barrier events of BK=32).
// LDS rows are 128 B; 16B-group index XORed with row&7 both at stage and
// read time -> uniform 2-way bank access per quarter-wave (free, m136).
// qkv_mode: N spans 3 concatenated 1024-col output buffers C0/C1/C2.
// rev_m: longest-work-first block order for triangular (causal/kcap) grids.
__global__ __launch_bounds__(256)
void gemm_nt(const bf16* __restrict__ A, int lda, size_t az,
             const bf16* __restrict__ B, int ldb, size_t bz,
             void* __restrict__ C0, void* __restrict__ C1, void* __restrict__ C2,
             int ldc, size_t cz,
             int M, int N, int K, float alpha,
             const float* __restrict__ bias,
             const float* __restrict__ row_scale, int rsz,
             int out_bf16, int qkv_mode, int causal_skip, int kcap,
             int row_off, int rev_m)
{
    int z  = blockIdx.z;
    int by = rev_m ? (gridDim.y - 1 - blockIdx.y) : blockIdx.y;
    int m0 = by * BM;
    int n0 = blockIdx.x * BN;
    if (causal_skip && n0 > row_off + m0 + BM - 1) return;  // above diagonal
    int Keff = kcap ? min(K, row_off + m0 + BM) : K;        // multiple of 128
    A += (size_t)z * az;
    B += (size_t)z * bz;

    __shared__ __attribute__((aligned(16))) bf16 As[BM * BK];  // 16 KB
    __shared__ __attribute__((aligned(16))) bf16 Bs[BN * BK];  // 16 KB

    int tid  = threadIdx.x;
    int lane = tid & 63;
    int q    = lane >> 4;    // 0..3  (k-subgroup)
    int r    = lane & 15;    // 0..15 (row-in-16)
    int wave = tid >> 6;
    int wm   = (wave >> 1) * 64;
    int wn   = (wave & 1) * 64;
    int sw   = r & 7;                                     // read-side swizzle
    int gsw  = (((tid & 7) ^ ((tid >> 3) & 7)) * 8);      // stage-side swizzle

    f32x4 acc[4][4];
#pragma unroll
    for (int i = 0; i < 4; i++)
#pragma unroll
        for (int j = 0; j < 4; j++) acc[i][j] = (f32x4){0.f, 0.f, 0.f, 0.f};

    // staging: 8 issues x 4 KB = 32 KB per k-tile. Thread tid owns LDS bytes
    // tid*16 (+4 KB per issue); fetches swizzled global k-group so LDS group
    // p of row rr holds global group p^(rr&7).
    const bf16* Ag = A + (size_t)(m0 + (tid >> 3)) * lda + gsw;
    const bf16* Bg = B + (size_t)(n0 + (tid >> 3)) * ldb + gsw;
    char* lAs = (char*)As + tid * 16;
    char* lBs = (char*)Bs + tid * 16;
    size_t astep = (size_t)32 * lda;
    size_t bstep = (size_t)32 * ldb;

    for (int k0 = 0; k0 < Keff; k0 += BK) {
#pragma unroll
        for (int i = 0; i < 4; i++) {
            async_copy16(Ag + k0 + i * astep, lAs + i * 4096);
            async_copy16(Bg + k0 + i * bstep, lBs + i * 4096);
        }
        asm volatile("s_waitcnt vmcnt(0)" ::: "memory");
        __syncthreads();

#pragma unroll
        for (int kk = 0; kk < 2; kk++) {
            bf16x8 av[4], bv[4];
#pragma unroll
            for (int mi = 0; mi < 4; mi++)
                av[mi] = *(const bf16x8*)&As[(wm + mi * 16 + r) * BK
                                            + (((kk << 2) + q) ^ sw) * 8];
#pragma unroll
            for (int ni = 0; ni < 4; ni++)
                bv[ni] = *(const bf16x8*)&Bs[(wn + ni * 16 + r) * BK
                                            + (((kk << 2) + q) ^ sw) * 8];
#pragma unroll
            for (int mi = 0; mi < 4; mi++)
#pragma unroll
                for (int ni = 0; ni < 4; ni++)
                    acc[mi][ni] = __builtin_amdgcn_mfma_f32_16x16x32_bf16(
                        av[mi], bv[ni], acc[mi][ni], 0, 0, 0);
        }
        __syncthreads();
    }

    const float* rs = row_scale ? row_scale + (size_t)z * rsz : nullptr;
    void* Cb = C0;
    if (qkv_mode) { int sel = n0 >> 10; Cb = sel == 0 ? C0 : (sel == 1 ? C1 : C2); }
    // epilogue: C/D layout col=lane&15, row=(lane>>4)*4+j  (m89-verified)
#pragma unroll
    for (int mi = 0; mi < 4; mi++) {
#pragma unroll
        for (int ni = 0; ni < 4; ni++) {
#pragma unroll
            for (int j = 0; j < 4; j++) {
                int row = m0 + wm + mi * 16 + q * 4 + j;
                int col = n0 + wn + ni * 16 + r;
                if (qkv_mode) col &= 1023;
                float v = acc[mi][ni][j] * alpha;
                if (rs)   v *= rs[row];
                if (bias) v += bias[col];
                if (out_bf16) ((bf16*)Cb + (size_t)z * cz)[(size_t)row * ldc + col] = (bf16)v;
                else          ((float*)Cb + (size_t)z * cz)[(size_t)row * ldc + col] = v;
            }
        }
    }
}

// One block per score row, bf16 scores in/out IN PLACE (row stride T bf16).
// Writes unnormalized P (zero-padded to the 128-block boundary) + 1/rowsum.
__global__ __launch_bounds__(256)
void softmax_causal(bf16* __restrict__ S, float* __restrict__ inv_l,
                    int T, int toff, int chunk)
{
    int tr = blockIdx.x, z = blockIdx.y;
    int t  = toff + tr;
    int L  = t + 1;
    int Lw = ((t >> 7) + 1) << 7;
    bf16* row = S + ((size_t)z * chunk + tr) * T;
    int tid = threadIdx.x;
    __shared__ float buf[4096];
    __shared__ float red[4];

    for (int s = tid * 8; s < Lw; s += 2048) {
        bf16x8 v = *(const bf16x8*)(row + s);
#pragma unroll
        for (int i = 0; i < 8; i++)
            buf[s + i] = (s + i < L) ? (float)v[i] : -3.0e38f;
    }
    __syncthreads();

    float m = -3.0e38f;
    for (int s = tid; s < Lw; s += 256) m = fmaxf(m, buf[s]);
#pragma unroll
    for (int off = 32; off > 0; off >>= 1) m = fmaxf(m, __shfl_down(m, off, 64));
    if ((tid & 63) == 0) red[tid >> 6] = m;
    __syncthreads();
    m = fmaxf(fmaxf(red[0], red[1]), fmaxf(red[2], red[3]));
    __syncthreads();

    float sum = 0.f;
    for (int s = tid * 8; s < Lw; s += 2048) {
        bf16x8 o;
#pragma unroll
        for (int i = 0; i < 8; i++) {
            float e = __expf(buf[s + i] - m);  // padded lanes -> 0
            sum += e;
            o[i] = (bf16)e;
        }
        *(bf16x8*)(row + s) = o;
    }
#pragma unroll
    for (int off = 32; off > 0; off >>= 1) sum += __shfl_down(sum, off, 64);
    if ((tid & 63) == 0) red[tid >> 6] = sum;
    __syncthreads();
    if (tid == 0) inv_l[(size_t)z * chunk + tr] = 1.0f / (red[0] + red[1] + red[2] + red[3]);
}

// batched transpose: V (B,T,C) -> VT (B,C,T), bf16
__global__ __launch_bounds__(256)
void transpose64(const bf16* __restrict__ V, bf16* __restrict__ VT, int T, int C)
{
    __shared__ bf16 tile[64][65];
    int b  = blockIdx.z;
    int s0 = blockIdx.x * 64, d0 = blockIdx.y * 64;
    const bf16* Vb  = V  + (size_t)b * T * C;
    bf16*       VTb = VT + (size_t)b * T * C;
    int tx = threadIdx.x & 63, ty = threadIdx.x >> 6;
#pragma unroll
    for (int i = 0; i < 64; i += 4)
        tile[ty + i][tx] = Vb[(size_t)(s0 + ty + i) * C + d0 + tx];
    __syncthreads();
#pragma unroll
    for (int i = 0; i < 64; i += 4)
        VTb[(size_t)(d0 + ty + i) * T + s0 + tx] = tile[tx][ty + i];
}

__global__ void cvt_f32_bf16(const float4* __restrict__ in, bf16x4* __restrict__ out, int n4)
{
    int i = blockIdx.x * blockDim.x + threadIdx.x;
    int stride = gridDim.x * blockDim.x;
    for (; i < n4; i += stride) {
        float4 v = in[i];
        bf16x4 o = { (bf16)v.x, (bf16)v.y, (bf16)v.z, (bf16)v.w };
        out[i] = o;
    }
}

extern "C" void kernel_launch(void* const* d_in, const int* in_sizes, int n_in,
                              void* d_out, int out_size, void* d_ws, size_t ws_size,
                              hipStream_t stream)
{
    const int B = 4, T = 4096, C = 1024, M = B * T;
    const float* x  = (const float*)d_in[0];
    const float* Wq = (const float*)d_in[1];
    const float* Wk = (const float*)d_in[2];
    const float* Wv = (const float*)d_in[3];
    const float* Wo = (const float*)d_in[4];
    const float* bo = (const float*)d_in[5];
    float* out = (float*)d_out;

    char* ws = (char*)d_ws;
    size_t off = 0;
    auto alloc = [&](size_t bytes) -> char* {
        char* p = ws + off;
        off += (bytes + 255) & ~(size_t)255;
        return p;
    };
    bf16* Wcat = (bf16*)alloc((size_t)3 * C * C * 2);  // [Wq; Wk; Wv]
    bf16* Wob  = (bf16*)alloc((size_t)C * C * 2);
    bf16* Qb   = (bf16*)alloc((size_t)M * C * 2);
    bf16* Kb   = (bf16*)alloc((size_t)M * C * 2);
    bf16* VT   = (bf16*)alloc((size_t)M * C * 2);

    // Preferred plan (chunk = T, ~232 MB — ws proven >= 235 MB in round 1):
    //   S region hosts xb and raw-V during projection (dead before S written);
    //   attention output O aliases Qb (Q dead after the single S-GEMM).
    size_t base = off;
    int chunk = T;
    bf16 *S, *xb, *Vtmp, *Ob;
    float* inv_l;
    {
        size_t need = base + (((size_t)B * T * T * 2 + 255) & ~(size_t)255)
                           + (((size_t)B * T * 4 + 255) & ~(size_t)255);
        if (need <= ws_size) {
            S     = (bf16*)alloc((size_t)B * T * T * 2);
            inv_l = (float*)alloc((size_t)B * T * 4);
            xb    = S;
            Vtmp  = S + (size_t)M * C;   // 32 MB past xb, inside S region
            Ob    = Qb;                  // O overwrites Q after S-GEMM
        } else {
            Ob = (bf16*)alloc((size_t)M * C * 2);
            chunk = T / 2;
            while (chunk > 1024) {
                size_t nd = off + (((size_t)B * chunk * T * 2 + 255) & ~(size_t)255)
                                + (((size_t)B * chunk * 4 + 255) & ~(size_t)255);
                if (nd <= ws_size) break;
                chunk >>= 1;
            }
            S     = (bf16*)alloc((size_t)B * chunk * T * 2);
            inv_l = (float*)alloc((size_t)B * chunk * 4);
            xb    = S;   // x dead after QKV projection
            Vtmp  = Ob;  // V staged in Ob, transposed before PV writes Ob
        }
    }

    dim3 blk(256);

    cvt_f32_bf16<<<dim3(4096), blk, 0, stream>>>((const float4*)x,  (bf16x4*)xb, M * C / 4);
    cvt_f32_bf16<<<dim3(1024), blk, 0, stream>>>((const float4*)Wq, (bf16x4*)(Wcat),             C * C / 4);
    cvt_f32_bf16<<<dim3(1024), blk, 0, stream>>>((const float4*)Wk, (bf16x4*)(Wcat + C * C),     C * C / 4);
    cvt_f32_bf16<<<dim3(1024), blk, 0, stream>>>((const float4*)Wv, (bf16x4*)(Wcat + 2 * C * C), C * C / 4);
    cvt_f32_bf16<<<dim3(1024), blk, 0, stream>>>((const float4*)Wo, (bf16x4*)Wob, C * C / 4);

    // fused QKV projection: [Q|K|V] = X * Wcat^T
    gemm_nt<<<dim3(3 * C / BN, M / BM, 1), blk, 0, stream>>>(
        xb, C, 0, Wcat, C, 0, Qb, Kb, Vtmp, C, 0, M, 3 * C, C, 1.f,
        nullptr, nullptr, 0, 1, 1, 0, 0, 0, 0);
    transpose64<<<dim3(T / 64, C / 64, B), blk, 0, stream>>>(Vtmp, VT, T, C);

    const float scale = 0.03125f;  // 1/sqrt(1024)
    for (int toff = 0; toff < T; toff += chunk) {
        // S = Q_chunk * K^T * scale  (bf16 out, causal skip, longest-m first)
        gemm_nt<<<dim3(T / BN, chunk / BM, B), blk, 0, stream>>>(
            Qb + (size_t)toff * C, C, (size_t)T * C,
            Kb, C, (size_t)T * C,
            S, nullptr, nullptr, T, (size_t)chunk * T,
            chunk, T, C, scale,
            nullptr, nullptr, 0, 1, 0, 1, 0, toff, 1);
        // causal softmax in place -> unnormalized bf16 P + 1/rowsum
        softmax_causal<<<dim3(chunk, B), blk, 0, stream>>>(S, inv_l, T, toff, chunk);
        // O = P * V  (NT vs VT, K capped at diagonal, scaled by 1/l, longest first)
        gemm_nt<<<dim3(C / BN, chunk / BM, B), blk, 0, stream>>>(
            S, T, (size_t)chunk * T,
            VT, T, (size_t)T * C,
            Ob + (size_t)toff * C, nullptr, nullptr, C, (size_t)T * C,
            chunk, C, T, 1.f,
            nullptr, inv_l, chunk, 1, 0, 0, 1, toff, 1);
    }

    // Y = O * Wo^T + bo  (fp32 out)
    gemm_nt<<<dim3(C / BN, M / BM, 1), blk, 0, stream>>>(
        Ob, C, 0, Wob, C, 0, out, nullptr, nullptr, C, 0, M, C, C, 1.f,
        bo, nullptr, 0, 0, 0, 0, 0, 0, 0);
}